// Round 1
// baseline (283.351 us; speedup 1.0000x reference)
//
#include <hip/hip_runtime.h>

namespace {

constexpr int K = 32;  // last-axis length

// One thread per row: load 32 f32 into registers, bitonic-sort (descending)
// a copy, cumsum, count support, select tau, write max(x - tau, 0).
// All array indices are compile-time after full unrolling (no scratch).
__global__ __launch_bounds__(256, 4)
void sparsemax_kernel(const float* __restrict__ x, float* __restrict__ out, int nrows) {
  const int stride = gridDim.x * blockDim.x;
  for (int row = blockIdx.x * blockDim.x + threadIdx.x; row < nrows; row += stride) {
    const float4* __restrict__ xp =
        reinterpret_cast<const float4*>(x) + (size_t)row * (K / 4);

    float orig[K];
#pragma unroll
    for (int i = 0; i < K / 4; ++i) {
      const float4 v = xp[i];
      orig[4 * i + 0] = v.x;
      orig[4 * i + 1] = v.y;
      orig[4 * i + 2] = v.z;
      orig[4 * i + 3] = v.w;
    }

    float r[K];
#pragma unroll
    for (int i = 0; i < K; ++i) r[i] = orig[i];

    // Bitonic sorting network, descending order. 240 compare-exchanges,
    // all indices compile-time constants after unroll.
#pragma unroll
    for (int kk = 2; kk <= K; kk <<= 1) {
#pragma unroll
      for (int j = kk >> 1; j > 0; j >>= 1) {
#pragma unroll
        for (int i = 0; i < K; ++i) {
          const int l = i ^ j;
          if (l > i) {
            const float a = r[i], b = r[l];
            const float mn = fminf(a, b);
            const float mx = fmaxf(a, b);
            if ((i & kk) == 0) {  // descending segment -> overall descending
              r[i] = mx; r[l] = mn;
            } else {
              r[i] = mn; r[l] = mx;
            }
          }
        }
      }
    }

    // cumsum + support count (reference: count of ALL j with
    // 1 + (j+1)*z_j - cumsum_j > 0; then gather cumsum at kz-1).
    float csum = 0.0f;
    int kz = 0;
#pragma unroll
    for (int j = 0; j < K; ++j) {
      csum += r[j];
      const float cond = 1.0f + (float)(j + 1) * r[j] - csum;
      kz += (cond > 0.0f) ? 1 : 0;
      r[j] = csum;  // r now holds cumsum
    }

    // Gather cumsum[kz-1] without runtime array indexing (cndmask chain).
    float csel = r[K - 1];
#pragma unroll
    for (int j = 0; j < K; ++j) csel = (kz == j + 1) ? r[j] : csel;

    const float tau = (csel - 1.0f) / (float)kz;

    float4* __restrict__ op =
        reinterpret_cast<float4*>(out) + (size_t)row * (K / 4);
#pragma unroll
    for (int i = 0; i < K / 4; ++i) {
      float4 o;
      o.x = fmaxf(orig[4 * i + 0] - tau, 0.0f);
      o.y = fmaxf(orig[4 * i + 1] - tau, 0.0f);
      o.z = fmaxf(orig[4 * i + 2] - tau, 0.0f);
      o.w = fmaxf(orig[4 * i + 3] - tau, 0.0f);
      op[i] = o;
    }
  }
}

}  // namespace

extern "C" void kernel_launch(void* const* d_in, const int* in_sizes, int n_in,
                              void* d_out, int out_size, void* d_ws, size_t ws_size,
                              hipStream_t stream) {
  const float* x = (const float*)d_in[0];
  float* out = (float*)d_out;
  const int nrows = in_sizes[0] / K;  // 4,194,304

  const int threads = 256;
  int blocks = (nrows + threads - 1) / threads;
  if (blocks > 2048) blocks = 2048;  // grid-stride; ~8 rows per thread

  hipLaunchKernelGGL(sparsemax_kernel, dim3(blocks), dim3(threads), 0, stream,
                     x, out, nrows);
}